// Round 4
// baseline (325.737 us; speedup 1.0000x reference)
//
#include <hip/hip_runtime.h>
#include <cstdint>
#include <cstddef>

typedef unsigned short u16;
typedef unsigned int   u32;

typedef short bf16x8 __attribute__((ext_vector_type(8)));
typedef float f32x4  __attribute__((ext_vector_type(4)));

// ---------------- helpers ----------------
__device__ __forceinline__ u16 f2bf(float f) {   // RNE f32 -> bf16
  u32 u = __float_as_uint(f);
  u += 0x7fffu + ((u >> 16) & 1u);
  return (u16)(u >> 16);
}
__device__ __forceinline__ float bflo(u32 w) { return __uint_as_float((w & 0xffffu) << 16); }
__device__ __forceinline__ float bfhi(u32 w) { return __uint_as_float(w & 0xffff0000u); }

#define GLB_AS(p) ((const __attribute__((address_space(1))) void*)(p))
#define LDS_AS(p) ((__attribute__((address_space(3))) void*)(p))

// ---------------- fused f32 -> bf16 convert: inputs + Wi + Wo ----------------
// quads: inputs 4194304, Wi 131072 (1024x512 f32), Wo 131072 (512x1024 f32)
// -> 4456448 quads = 17408 blocks x 256 exactly.
// (R3 bug: used 32768 quads for the weights -> 3/4 of each weight stayed
//  0xAA poison ~= 0 in bf16 -> absmax 5.59. R2's conv2 had 131072.)
__global__ __launch_bounds__(256)
void conv3_f32_bf16(const float* __restrict__ in, u16* __restrict__ a,
                    const float* __restrict__ wi, u16* __restrict__ wib,
                    const float* __restrict__ wo, u16* __restrict__ wob)
{
  long i = (long)blockIdx.x * 256 + threadIdx.x;
  const float* src; u16* dst;
  if (i < 4194304L) { src = in; dst = a; }
  else if (i < 4325376L) { i -= 4194304L; src = wi; dst = wib; }
  else { i -= 4325376L; if (i >= 131072L) return; src = wo; dst = wob; }
  float4 v = ((const float4*)src)[i];
  u32 lo = (u32)f2bf(v.x) | ((u32)f2bf(v.y) << 16);
  u32 hi = (u32)f2bf(v.z) | ((u32)f2bf(v.w) << 16);
  ((uint2*)dst)[i] = make_uint2(lo, hi);
}

// ---------------- wave-private bf16 GEMM: C[m,n] = sum_k A[m,k]*W[n,k] -------
// NO barriers: workgroup = 1 wave, 64x64 tile, BK=32, double-buffered private
// LDS (8 KB + 8 KB). Per-wave `s_waitcnt vmcnt(8)` retires the older tile's 8
// DMAs while the newer tile's 8 stream (AITER-style; expressible because no
// __syncthreads drain exists). Bias is loaded to registers and the VMEM queue
// drained BEFORE the prologue, so in-loop vmcnt counts ONLY our DMAs.
// Swizzle (R2-verified, 0 conflicts): granule g holds row r=g>>2,
// k8 = (g&3)^((r>>1)&3); fragment (m,q) reads granule m*4 + (q^((m>>1)&3)).
template<int OUT_BF16, int RELU>
__global__ __launch_bounds__(64)
void gemm_wt(const u16* __restrict__ A, const u16* __restrict__ Bw,
             const float* __restrict__ bias, void* __restrict__ Cout,
             int M, int N, int K, int lognb)
{
  __shared__ __align__(16) u16 As[2][64 * 32];
  __shared__ __align__(16) u16 Bs[2][64 * 32];

  const int lane = threadIdx.x;
  const int bid  = blockIdx.x;
  const int m0 = (bid >> lognb) * 64;
  const int n0 = (bid & ((1 << lognb) - 1)) * 64;

  f32x4 acc[4][4];
#pragma unroll
  for (int i = 0; i < 4; ++i)
#pragma unroll
    for (int j = 0; j < 4; ++j) acc[i][j] = f32x4{0.f, 0.f, 0.f, 0.f};

  // DMA source addresses: instr i covers granules i*64+lane
  const u16* Ap[4]; const u16* Bp[4];
#pragma unroll
  for (int i = 0; i < 4; ++i) {
    int g = i * 64 + lane;
    int r = g >> 2;
    int c = ((g & 3) ^ ((r >> 1) & 3)) << 3;
    Ap[i] = A  + (size_t)(m0 + r) * K + c;
    Bp[i] = Bw + (size_t)(n0 + r) * K + c;
  }
  // fragment granule offsets (identical geometry for A and B panels)
  const int fm = lane & 15;
  const int q  = lane >> 4;
  int foff[4];
#pragma unroll
  for (int i = 0; i < 4; ++i) {
    int m = i * 16 + fm;
    foff[i] = (m * 4 + (q ^ ((m >> 1) & 3))) * 8;
  }

  // bias -> registers BEFORE any DMA, then drain: keeps in-loop vmcnt pure.
  const int colL = lane & 15;
  float bvv[4];
#pragma unroll
  for (int ni = 0; ni < 4; ++ni) bvv[ni] = bias[n0 + ni * 16 + colL];
  asm volatile("s_waitcnt vmcnt(0)" ::: "memory");

#define ISSUE_TILE(kk, buf)                                                        \
  {                                                                                \
    u16* la_ = &As[buf][0]; u16* lb_ = &Bs[buf][0];                                \
    _Pragma("unroll")                                                              \
    for (int i = 0; i < 4; ++i)                                                    \
      __builtin_amdgcn_global_load_lds(GLB_AS(Ap[i] + (kk)), LDS_AS(la_ + i*512), 16, 0, 0); \
    _Pragma("unroll")                                                              \
    for (int i = 0; i < 4; ++i)                                                    \
      __builtin_amdgcn_global_load_lds(GLB_AS(Bp[i] + (kk)), LDS_AS(lb_ + i*512), 16, 0, 0); \
  }

#define COMPUTE_TILE(buf)                                                          \
  {                                                                                \
    const u16* la_ = &As[buf][0]; const u16* lb_ = &Bs[buf][0];                    \
    bf16x8 af[4], bf[4];                                                           \
    _Pragma("unroll")                                                              \
    for (int i = 0; i < 4; ++i) { af[i] = *(const bf16x8*)(la_ + foff[i]);         \
                                  bf[i] = *(const bf16x8*)(lb_ + foff[i]); }       \
    _Pragma("unroll")                                                              \
    for (int mi = 0; mi < 4; ++mi)                                                 \
      _Pragma("unroll")                                                            \
      for (int ni = 0; ni < 4; ++ni)                                               \
        acc[mi][ni] = __builtin_amdgcn_mfma_f32_16x16x32_bf16(af[mi], bf[ni],      \
                                                              acc[mi][ni], 0, 0, 0); \
  }

  // prologue: fill both buffers (16 DMAs in flight)
  ISSUE_TILE(0, 0)
  ISSUE_TILE(32, 1)

  // K is a multiple of 64 (512 / 1024)
  for (int kt = 0; kt < K; kt += 64) {
    const bool more = (kt + 64) < K;
    if (more) {
      asm volatile("s_waitcnt vmcnt(8)" ::: "memory");   // tile kt landed
      COMPUTE_TILE(0)
      ISSUE_TILE(kt + 64, 0)                              // refill buf0
      asm volatile("s_waitcnt vmcnt(8)" ::: "memory");   // tile kt+32 landed
      COMPUTE_TILE(1)
      ISSUE_TILE(kt + 96, 1)                              // refill buf1
    } else {
      asm volatile("s_waitcnt vmcnt(8)" ::: "memory");   // tile kt landed
      COMPUTE_TILE(0)
      asm volatile("s_waitcnt vmcnt(0)" ::: "memory");   // last tile landed
      COMPUTE_TILE(1)
    }
  }
#undef ISSUE_TILE
#undef COMPUTE_TILE

  // epilogue: C/D layout col=lane&15, row=(lane>>4)*4+reg
  const int rowQ = (lane >> 4) * 4;
#pragma unroll
  for (int mi = 0; mi < 4; ++mi) {
#pragma unroll
    for (int ni = 0; ni < 4; ++ni) {
      int col  = n0 + ni * 16 + colL;
      int rowb = m0 + mi * 16 + rowQ;
#pragma unroll
      for (int r = 0; r < 4; ++r) {
        float v = acc[mi][ni][r] + bvv[ni];
        if (RELU) v = fmaxf(v, 0.f);
        size_t idx = (size_t)(rowb + r) * N + col;
        if (OUT_BF16) ((u16*)Cout)[idx] = f2bf(v);
        else          ((float*)Cout)[idx] = v;
      }
    }
  }
}

// ---------------- scan pass 1: per-chunk end state ----------------
__global__ __launch_bounds__(512)
void scan_chunk_end(const u16* __restrict__ u, const float* __restrict__ plog,
                    float2* __restrict__ e)
{
  const int j = threadIdx.x;   // channel 0..511
  const int c = blockIdx.x;    // chunk 0..31
  const int b = blockIdx.y;    // batch 0..7
  float vv  = expf(plog[j]);
  float th  = expf(plog[512 + j]);
  float mag = expf(-vv);
  float lr = mag * cosf(th), li = mag * sinf(th);
  const u32* up = (const u32*)u;
  size_t idx = (size_t)(b * 4096 + c * 128) * 512 + j;
  float hr = 0.f, hi = 0.f;
#pragma unroll 8
  for (int t = 0; t < 128; ++t) {
    u32 w = up[idx]; idx += 512;
    float ur = bflo(w), ui = bfhi(w);
    float nr = fmaf(lr, hr, fmaf(-li, hi, ur));
    float ni2 = fmaf(lr, hi, fmaf(li, hr, ui));
    hr = nr; hi = ni2;
  }
  e[(size_t)(b * 32 + c) * 512 + j] = make_float2(hr, hi);
}

// ---------------- scan pass 2 (fused carry + output) ----------------
// carry_c = sum_{i<c} Lambda^{c-1-i} * e_i  (Lambda = lambda^128), computed
// per block from the tiny L2-resident e array; then local rescan writes xr.
__global__ __launch_bounds__(512)
void scan_out2(const u16* __restrict__ u, const float* __restrict__ plog,
               const float2* __restrict__ e, u16* __restrict__ xr)
{
  const int j = threadIdx.x;
  const int c = blockIdx.x;
  const int b = blockIdx.y;
  float vv  = expf(plog[j]);
  float th  = expf(plog[512 + j]);
  float gm  = expf(plog[1024 + j]);
  float mag = expf(-vv);
  float lr = mag * cosf(th), li = mag * sinf(th);

  // carry from chunk-end states
  float Lm = expf(-128.f * vv);
  float La = 128.f * th;
  float Lr = Lm * cosf(La), Li = Lm * sinf(La);   // lambda^128
  float hr = 0.f, hi = 0.f;
  for (int i = 0; i < c; ++i) {
    float2 ec = e[(size_t)(b * 32 + i) * 512 + j];
    float nr = fmaf(Lr, hr, fmaf(-Li, hi, ec.x));
    float ni2 = fmaf(Lr, hi, fmaf(Li, hr, ec.y));
    hr = nr; hi = ni2;
  }

  const u32* up = (const u32*)u;
  size_t uidx = (size_t)(b * 4096 + c * 128) * 512 + j;
  size_t xidx = (size_t)(b * 4096 + c * 128) * 1024 + j;
#pragma unroll 4
  for (int t = 0; t < 128; ++t) {
    u32 w = up[uidx]; uidx += 512;
    float ur = bflo(w), ui = bfhi(w);
    float nr = fmaf(lr, hr, fmaf(-li, hi, ur));
    float ni2 = fmaf(lr, hi, fmaf(li, hr, ui));
    hr = nr; hi = ni2;
    xr[xidx]       = f2bf(gm * hr);
    xr[xidx + 512] = f2bf(gm * hi);
    xidx += 1024;
  }
}

// ---------------- launch ----------------
extern "C" void kernel_launch(void* const* d_in, const int* in_sizes, int n_in,
                              void* d_out, int out_size, void* d_ws, size_t ws_size,
                              hipStream_t stream)
{
  (void)in_sizes; (void)n_in; (void)out_size; (void)ws_size;
  const float* inputs = (const float*)d_in[0];
  const float* Wi     = (const float*)d_in[1];
  const float* bi     = (const float*)d_in[2];
  const float* Wo     = (const float*)d_in[3];
  const float* bo     = (const float*)d_in[4];
  const float* plog   = (const float*)d_in[5];

  char* ws = (char*)d_ws;
  u16*    xrA   = (u16*)(ws);                        // A_bf then xr_bf
  u16*    u_bf  = (u16*)(ws + 67108864ull);
  u16*    Wi_bf = (u16*)(ws + 134217728ull);
  u16*    Wo_bf = (u16*)(ws + 135266304ull);
  float2* e_b   = (float2*)(ws + 136314880ull);

  // 1) convert all three fp32 tensors to bf16 (one launch)
  conv3_f32_bf16<<<17408, 256, 0, stream>>>(inputs, xrA, Wi, Wi_bf, Wo, Wo_bf);

  // 2) u = X @ Wi^T + bi   (M=32768, N=1024, K=512), bf16 out
  gemm_wt<1, 0><<<8192, 64, 0, stream>>>(xrA, Wi_bf, bi, u_bf,
                                         32768, 1024, 512, 4);

  // 3) chunked complex prefix scan + gamma, write xr (bf16) over A region
  scan_chunk_end<<<dim3(32, 8), 512, 0, stream>>>(u_bf, plog, e_b);
  scan_out2<<<dim3(32, 8), 512, 0, stream>>>(u_bf, plog, e_b, xrA);

  // 4) out = relu(xr @ Wo^T + bo)  (M=32768, N=512, K=1024), fp32 out
  gemm_wt<0, 1><<<4096, 64, 0, stream>>>(xrA, Wo_bf, bo, d_out,
                                         32768, 512, 1024, 3);
}